// Round 7
// baseline (204.885 us; speedup 1.0000x reference)
//
#include <hip/hip_runtime.h>
#include <hip/hip_bf16.h>
#include <stdint.h>

// Problem dims
#define B_  16
#define T_  2048
#define D_  512
#define I_  1024
#define K_  31
#define M_  (B_ * T_)   // 32768

typedef __attribute__((ext_vector_type(8))) __bf16 bf16x8;
typedef __attribute__((ext_vector_type(4))) float  f32x4;

__device__ __forceinline__ unsigned short f2bf(float f) {
    union { float f; uint32_t u; } v; v.f = f;
    uint32_t u = v.u;
    uint32_t r = (u + 0x7FFFu + ((u >> 16) & 1u)) >> 16;
    return (unsigned short)r;
}
__device__ __forceinline__ float bf2f(unsigned short h) {
    union { uint32_t u; float f; } v; v.u = ((uint32_t)h) << 16;
    return v.f;
}

__device__ __forceinline__ void gload_lds16(const void* g, void* l) {
    __builtin_amdgcn_global_load_lds(
        (const __attribute__((address_space(1))) unsigned int*)g,
        (__attribute__((address_space(3))) unsigned int*)l, 16, 0, 0);
}

// ---------------- prep: cast weights to bf16 ----------------
__global__ __launch_bounds__(256) void prep_weights(
    const float* __restrict__ w1, const float* __restrict__ w2,
    unsigned short* __restrict__ w1b, unsigned short* __restrict__ w2b)
{
    int i = blockIdx.x * 256 + threadIdx.x;
    const int n1 = 2 * I_ * D_;
    const int n2 = D_ * I_;
    if (i < n1) w1b[i] = f2bf(w1[i]);
    if (i < n2) w2b[i] = f2bf(w2[i]);
}

// ---------------- LayerNorm: fp32 -> bf16 xn ----------------
__global__ __launch_bounds__(256) void ln_kernel(
    const float* __restrict__ x, const float* __restrict__ gam,
    const float* __restrict__ bet, unsigned short* __restrict__ xn)
{
    int row  = blockIdx.x * 4 + (threadIdx.x >> 6);
    int lane = threadIdx.x & 63;
    const float* xr = x + (size_t)row * D_ + lane * 8;
    float4 a0 = *(const float4*)xr;
    float4 a1 = *(const float4*)(xr + 4);
    float xs[8] = {a0.x, a0.y, a0.z, a0.w, a1.x, a1.y, a1.z, a1.w};

    float s = xs[0]+xs[1]+xs[2]+xs[3]+xs[4]+xs[5]+xs[6]+xs[7];
    #pragma unroll
    for (int off = 32; off; off >>= 1) s += __shfl_xor(s, off);
    float mu = s * (1.0f / D_);

    float q = 0.f;
    #pragma unroll
    for (int j = 0; j < 8; ++j) { float d = xs[j] - mu; q += d * d; }
    #pragma unroll
    for (int off = 32; off; off >>= 1) q += __shfl_xor(q, off);
    float rstd = rsqrtf(q * (1.0f / D_) + 1e-5f);

    float4 g0 = *(const float4*)(gam + lane * 8);
    float4 g1 = *(const float4*)(gam + lane * 8 + 4);
    float4 e0 = *(const float4*)(bet + lane * 8);
    float4 e1 = *(const float4*)(bet + lane * 8 + 4);
    float gs[8] = {g0.x, g0.y, g0.z, g0.w, g1.x, g1.y, g1.z, g1.w};
    float bs[8] = {e0.x, e0.y, e0.z, e0.w, e1.x, e1.y, e1.z, e1.w};

    unsigned short o[8];
    #pragma unroll
    for (int j = 0; j < 8; ++j) o[j] = f2bf((xs[j] - mu) * rstd * gs[j] + bs[j]);
    uint4 pk;
    pk.x = (uint32_t)o[0] | ((uint32_t)o[1] << 16);
    pk.y = (uint32_t)o[2] | ((uint32_t)o[3] << 16);
    pk.z = (uint32_t)o[4] | ((uint32_t)o[5] << 16);
    pk.w = (uint32_t)o[6] | ((uint32_t)o[7] << 16);
    *(uint4*)(xn + (size_t)row * D_ + lane * 8) = pk;
}

// ======================================================================
// 256-row GEMM engine, BK=32, 4 LDS buffers, prefetch distance 3,
// counted vmcnt(8), ONE barrier per K-tile.
// LDS: buffer c at c*32768: A [256][32]bf16 @0, B [256][32]bf16 @16384.
// Row = 64 B = 4 slots of 16 B. Swizzle: LDS[row][slot] holds
// global[row][slot ^ (row&3)]; gload dest linear (dest=tid*16), source
// pre-swizzled; reads XOR the slot the same way -> conflict-free b128.
// Per K-tile t: read 12 frags from buf[t%4]; issue 4 gloads->buf[(t+3)%4]
// (that buffer was fully consumed before barrier t-1); 32 MFMA;
// lgkm(0); vmcnt(8) (tiles t+1,t+2 stay in flight); barrier.
// Tail: vmcnt 8 -> 4 -> 0 -> none.
// ======================================================================

#define VMCNT(n) asm volatile("s_waitcnt vmcnt(" #n ")" ::: "memory")

#define RD4(c, base, idx) (*(const bf16x8*)(lds + (c) * 32768 + (base) + (idx) * 1024))
#define MF(m, n, a, b) \
    acc[m][n] = __builtin_amdgcn_mfma_f32_16x16x32_bf16(a, b, acc[m][n], 0, 0, 0)

#define ISSUE4(c) do { \
    gload_lds16(agA[0], lds + (c) * 32768 +         tid * 16); agA[0] += 32; \
    gload_lds16(agA[1], lds + (c) * 32768 +  8192 + tid * 16); agA[1] += 32; \
    gload_lds16(agB[0], lds + (c) * 32768 + 16384 + tid * 16); agB[0] += 32; \
    gload_lds16(agB[1], lds + (c) * 32768 + 24576 + tid * 16); agB[1] += 32; \
} while (0)

#define LGKM_SCHED() do { \
    asm volatile("s_waitcnt lgkmcnt(0)" ::: "memory"); \
    __builtin_amdgcn_sched_barrier(0); } while (0)

// One K-tile: CUR = t%4 (compile-time), DOISS, VM in {8,4,0,-1}
#define KT(CUR, DOISS, VM) do { \
    bf16x8 b0,b1,b2,b3, a0,a1,a2,a3,a4,a5,a6,a7; \
    b0 = RD4(CUR, rB, 0); b1 = RD4(CUR, rB, 1); b2 = RD4(CUR, rB, 2); b3 = RD4(CUR, rB, 3); \
    a0 = RD4(CUR, rA, 0); a1 = RD4(CUR, rA, 1); a2 = RD4(CUR, rA, 2); a3 = RD4(CUR, rA, 3); \
    a4 = RD4(CUR, rA, 4); a5 = RD4(CUR, rA, 5); a6 = RD4(CUR, rA, 6); a7 = RD4(CUR, rA, 7); \
    if (DOISS) { ISSUE4((CUR + 3) & 3); } \
    __builtin_amdgcn_s_setprio(1); \
    MF(0,0,a0,b0); MF(0,1,a0,b1); MF(0,2,a0,b2); MF(0,3,a0,b3); \
    MF(1,0,a1,b0); MF(1,1,a1,b1); MF(1,2,a1,b2); MF(1,3,a1,b3); \
    MF(2,0,a2,b0); MF(2,1,a2,b1); MF(2,2,a2,b2); MF(2,3,a2,b3); \
    MF(3,0,a3,b0); MF(3,1,a3,b1); MF(3,2,a3,b2); MF(3,3,a3,b3); \
    MF(4,0,a4,b0); MF(4,1,a4,b1); MF(4,2,a4,b2); MF(4,3,a4,b3); \
    MF(5,0,a5,b0); MF(5,1,a5,b1); MF(5,2,a5,b2); MF(5,3,a5,b3); \
    MF(6,0,a6,b0); MF(6,1,a6,b1); MF(6,2,a6,b2); MF(6,3,a6,b3); \
    MF(7,0,a7,b0); MF(7,1,a7,b1); MF(7,2,a7,b2); MF(7,3,a7,b3); \
    __builtin_amdgcn_s_setprio(0); \
    LGKM_SCHED(); \
    if ((VM) == 8) { VMCNT(8); } else if ((VM) == 4) { VMCNT(4); } \
    else if ((VM) == 0) { VMCNT(0); } \
    __builtin_amdgcn_s_barrier(); \
} while (0)

// ---------------- GEMM1: 1024 blocks, 256 rows x 128 channels each.
// xn[32768,512] x w1b^T -> SwiGLU -> u bf16 [32768,1024]
// B-tile row n: gate = n&16, channel = jb*128 + (n>>5)*16 + (n&15).
__global__ __launch_bounds__(512, 2) void gemm1_kernel(
    const unsigned short* __restrict__ xn,
    const unsigned short* __restrict__ w1b,
    const float* __restrict__ b1,
    unsigned short* __restrict__ u)
{
    __shared__ __align__(16) unsigned char lds[131072];
    const int tid  = threadIdx.x;
    const int lane = tid & 63;
    const int wv   = tid >> 6;
    const int wm   = wv >> 2;   // 0..1
    const int wn   = wv & 3;    // 0..3

    const int bid = blockIdx.x;                 // nwg = 1024
    const int sw  = (bid & 7) * 128 + (bid >> 3);
    const int jb  = sw & 7;
    const int m0  = (sw >> 3) * 256;

    const unsigned short* agA[2];
    const unsigned short* agB[2];
    {
        const int srow = tid >> 2;              // 0..127
        const int scb  = tid & 3;               // 16B slot
        #pragma unroll
        for (int j = 0; j < 2; ++j) {
            int row = j * 128 + srow;
            int kk  = (scb ^ (row & 3)) * 8;
            agA[j] = xn + (size_t)(m0 + row) * D_ + kk;
            int chl  = ((row >> 5) << 4) + (row & 15);
            int wrow = ((row & 16) ? 1024 : 0) + jb * 128 + chl;
            agB[j] = w1b + (size_t)wrow * D_ + kk;
        }
    }

    const int l15 = lane & 15;
    const unsigned slotx = (unsigned)(((lane >> 4) ^ (l15 & 3)) << 4);
    const unsigned rA = (unsigned)(wm * 128 + l15) * 64 + slotx;
    const unsigned rB = 16384u + (unsigned)(wn * 64 + l15) * 64 + slotx;

    f32x4 acc[8][4];
    #pragma unroll
    for (int i = 0; i < 8; ++i)
        #pragma unroll
        for (int n = 0; n < 4; ++n) acc[i][n] = (f32x4){0.f, 0.f, 0.f, 0.f};

    // prologue: stage tiles 0,1,2
    ISSUE4(0); ISSUE4(1); ISSUE4(2);
    VMCNT(8);
    __builtin_amdgcn_s_barrier();

    // NT = 16 K-tiles (BK=32, K=512)
    #pragma unroll 1
    for (int h = 0; h < 3; ++h) {               // t = 0..11
        KT(0, true, 8); KT(1, true, 8); KT(2, true, 8); KT(3, true, 8);
    }
    KT(0, true,  8);                             // t12 (stages t15)
    KT(1, false, 4);                             // t13
    KT(2, false, 0);                             // t14
    KT(3, false, -1);                            // t15

    // epilogue: SwiGLU, frag-local a/g pairing
    const int rQ = (lane >> 4) * 4;
    #pragma unroll
    for (int p = 0; p < 2; ++p) {
        int ch = jb * 128 + wn * 32 + p * 16 + l15;
        float ba = b1[ch];
        float bg = b1[1024 + ch];
        #pragma unroll
        for (int mf = 0; mf < 8; ++mf) {
            #pragma unroll
            for (int r = 0; r < 4; ++r) {
                float a = acc[mf][2 * p][r] + ba;
                float g = acc[mf][2 * p + 1][r] + bg;
                float sg = g * __builtin_amdgcn_rcpf(1.0f + __expf(-g));
                int row = m0 + wm * 128 + mf * 16 + rQ + r;
                u[(size_t)row * I_ + ch] = f2bf(a * sg);
            }
        }
    }
}

// ---------------- depthwise conv K=31 + bias + PReLU: u bf16 -> v bf16 ----------------
__global__ __launch_bounds__(256) void dwconv_kernel(
    const unsigned short* __restrict__ u, const float* __restrict__ dw,
    const float* __restrict__ dwb, const float* __restrict__ alpha,
    unsigned short* __restrict__ v)
{
    __shared__ __align__(16) unsigned short su[286][64];
    const int tid     = threadIdx.x;
    const int c0      = blockIdx.y * 64;
    const int b       = blockIdx.z;
    const int tile_t0 = blockIdx.x * 256;

    #pragma unroll
    for (int it = 0; it < 9; ++it) {
        int r = it * 32 + (tid >> 3);
        if (r < 286) {
            int tt = tile_t0 - 15 + r;
            int cc = (tid & 7) * 8;
            uint4 val = {0u, 0u, 0u, 0u};
            if (tt >= 0 && tt < T_)
                val = *(const uint4*)(u + ((size_t)b * T_ + tt) * I_ + c0 + cc);
            *(uint4*)(&su[r][cc]) = val;
        }
    }
    __syncthreads();

    const int c  = tid & 63;
    const int tb = (tid >> 6) * 64;

    float dwk[K_];
    #pragma unroll
    for (int k = 0; k < K_; ++k) dwk[k] = dw[(c0 + c) * K_ + k];
    const float bia = dwb[c0 + c], al = alpha[c0 + c];

    unsigned short* vb = v + ((size_t)b * T_ + tile_t0 + tb) * I_ + c0 + c;

    #pragma unroll
    for (int chk = 0; chk < 4; ++chk) {
        float w[46];
        #pragma unroll
        for (int j = 0; j < 46; ++j)
            w[j] = bf2f(su[tb + chk * 16 + j][c]);
        #pragma unroll
        for (int i = 0; i < 16; ++i) {
            float acc = bia;
            #pragma unroll
            for (int k = 0; k < K_; ++k) acc += w[i + k] * dwk[k];
            float o = acc > 0.f ? acc : al * acc;
            vb[(size_t)(chk * 16 + i) * I_] = f2bf(o);
        }
    }
}

// ---------------- GEMM2: v[32768,1024] x w2b^T + b2 -> out fp32 [32768,512] ----------------
__global__ __launch_bounds__(512, 2) void gemm2_kernel(
    const unsigned short* __restrict__ v,
    const unsigned short* __restrict__ w2b,
    const float* __restrict__ b2,
    float* __restrict__ out)
{
    __shared__ __align__(16) unsigned char lds[131072];
    const int tid  = threadIdx.x;
    const int lane = tid & 63;
    const int wv   = tid >> 6;
    const int wm   = wv >> 2;
    const int wn   = wv & 3;

    const int bid = blockIdx.x;                 // 256 blocks
    const int sw  = (bid & 7) * 32 + (bid >> 3);
    const int n0  = (sw & 1) * 256;
    const int m0  = (sw >> 1) * 256;

    const unsigned short* agA[2];
    const unsigned short* agB[2];
    {
        const int srow = tid >> 2;
        const int scb  = tid & 3;
        #pragma unroll
        for (int j = 0; j < 2; ++j) {
            int row = j * 128 + srow;
            int kk  = (scb ^ (row & 3)) * 8;
            agA[j] = v   + (size_t)(m0 + row) * I_ + kk;
            agB[j] = w2b + (size_t)(n0 + row) * I_ + kk;
        }
    }

    const int l15 = lane & 15;
    const unsigned slotx = (unsigned)(((lane >> 4) ^ (l15 & 3)) << 4);
    const unsigned rA = (unsigned)(wm * 128 + l15) * 64 + slotx;
    const unsigned rB = 16384u + (unsigned)(wn * 64 + l15) * 64 + slotx;

    f32x4 acc[8][4];
    #pragma unroll
    for (int i = 0; i < 8; ++i)
        #pragma unroll
        for (int n = 0; n < 4; ++n) acc[i][n] = (f32x4){0.f, 0.f, 0.f, 0.f};

    ISSUE4(0); ISSUE4(1); ISSUE4(2);
    VMCNT(8);
    __builtin_amdgcn_s_barrier();

    // NT = 32 K-tiles (BK=32, K=1024)
    #pragma unroll 1
    for (int h = 0; h < 7; ++h) {               // t = 0..27
        KT(0, true, 8); KT(1, true, 8); KT(2, true, 8); KT(3, true, 8);
    }
    KT(0, true,  8);                             // t28 (stages t31)
    KT(1, false, 4);                             // t29
    KT(2, false, 0);                             // t30
    KT(3, false, -1);                            // t31

    const int rQ = (lane >> 4) * 4;
    #pragma unroll
    for (int nf = 0; nf < 4; ++nf) {
        int col = n0 + wn * 64 + nf * 16 + l15;
        float bb = b2[col];
        #pragma unroll
        for (int mf = 0; mf < 8; ++mf) {
            #pragma unroll
            for (int r = 0; r < 4; ++r) {
                int row = m0 + wm * 128 + mf * 16 + rQ + r;
                out[(size_t)row * D_ + col] = acc[mf][nf][r] + bb;
            }
        }
    }
}

extern "C" void kernel_launch(void* const* d_in, const int* in_sizes, int n_in,
                              void* d_out, int out_size, void* d_ws, size_t ws_size,
                              hipStream_t stream) {
    const float* x     = (const float*)d_in[0];
    const float* ln_g  = (const float*)d_in[1];
    const float* ln_b  = (const float*)d_in[2];
    const float* w1    = (const float*)d_in[3];
    const float* b1    = (const float*)d_in[4];
    const float* dw    = (const float*)d_in[5];
    const float* dwb   = (const float*)d_in[6];
    const float* alpha = (const float*)d_in[7];
    const float* w2    = (const float*)d_in[8];
    const float* b2    = (const float*)d_in[9];
    float* out = (float*)d_out;

    char* ws = (char*)d_ws;
    unsigned short* xn  = (unsigned short*)(ws);                 // 32 MB
    unsigned short* u   = (unsigned short*)(ws + 33554432);      // 64 MB
    unsigned short* v   = (unsigned short*)(ws + 100663296);     // 64 MB
    unsigned short* w1b = (unsigned short*)(ws + 167772160);     // 2 MB
    unsigned short* w2b = (unsigned short*)(ws + 169869312);     // 1 MB

    prep_weights<<<4096, 256, 0, stream>>>(w1, w2, w1b, w2b);
    ln_kernel<<<M_ / 4, 256, 0, stream>>>(x, ln_g, ln_b, xn);
    gemm1_kernel<<<(M_ / 256) * (I_ / 128), 512, 0, stream>>>(xn, w1b, b1, u);  // 1024
    dim3 gc(T_ / 256, I_ / 64, B_);
    dwconv_kernel<<<gc, 256, 0, stream>>>(u, dw, dwb, alpha, v);
    gemm2_kernel<<<256, 512, 0, stream>>>(v, w2b, b2, out);
}